// Round 1
// baseline (211.275 us; speedup 1.0000x reference)
//
#include <hip/hip_runtime.h>
#include <math.h>

// TreeAttention: hierarchical top-k mask refinement + sparse attention.
// N=8, T_DST=512, T_SRC=4096, HID=64, K=64, W0=64, SCALE_UP=2, OVERSAMPLE=1.5
//
// One block (128 threads, 2 waves) per (n, a) row; 4096 rows total.
// sort+dedup+truncate is replaced by a 4096-bit LDS bitmap (exact semantics:
// ascending unique values, first max_z kept).

#define TSRC_N 4096
#define TDST_N 512
#define HID_N  64
#define NEGV   -32000.0f

__global__ __launch_bounds__(128)
void tree_attn_kernel(const float* __restrict__ q,
                      const float* __restrict__ k,
                      const float* __restrict__ v,
                      float* __restrict__ out)
{
    const int row = blockIdx.x;            // 0..4095
    const int n   = row >> 9;              // row / 512
    const int a   = row & 511;
    const float tsrc = (float)(TSRC_N - TDST_N + 1 + a);   // 3585 + a
    const int tid = threadIdx.x;

    __shared__ __align__(16) float q_s[HID_N];
    __shared__ int            pix_s[128];
    __shared__ unsigned char  msk_s[128];
    __shared__ float          sc_s[128];
    __shared__ unsigned int   bm[128];     // 4096-bit presence bitmap
    __shared__ double         p_s[64];

    const float* kb = k + (size_t)n * TSRC_N * HID_N;
    const float* vb = v + (size_t)n * TSRC_N * HID_N;

    if (tid < HID_N) q_s[tid] = q[(size_t)row * HID_N + tid];
    // iteration 0 state: pixels = arange(96), pmask = arange(96) < 64
    pix_s[tid] = tid;
    msk_s[tid] = (tid < 64) ? 1 : 0;
    __syncthreads();

    float ws = 64.0f;
    int Z = 96;

    for (int it = 0; it < 7; ++it) {
        const bool  last    = (it == 6);
        const float mult    = last ? 1.0f : 1.5f;
        const int   tks_max = (it == 0) ? 63 : (last ? 64 : 96);
        const int   max_z   = last ? 64 : 128;

        // ---- scores: s[z] = mask ? q . k[round(pix * tsrc/ws)] : NEG ----
        float myscore = NEGV;
        if (tid < Z) {
            if (msk_s[tid]) {
                const float r = tsrc / ws;                 // exact f32 (pow2 or ==1)
                int tx = (int)rintf((float)pix_s[tid] * r); // exact product, half-even
                tx = tx < (TSRC_N - 1) ? tx : (TSRC_N - 1);
                const float4* k4 = (const float4*)(kb + (size_t)tx * HID_N);
                const float4* q4 = (const float4*)q_s;
                double acc = 0.0;
                #pragma unroll
                for (int h4 = 0; h4 < HID_N / 4; ++h4) {
                    const float4 kv = k4[h4];
                    const float4 qv = q4[h4];
                    acc = fma((double)qv.x, (double)kv.x, acc);
                    acc = fma((double)qv.y, (double)kv.y, acc);
                    acc = fma((double)qv.z, (double)kv.z, acc);
                    acc = fma((double)qv.w, (double)kv.w, acc);
                }
                myscore = (float)acc;
            }
            sc_s[tid] = myscore;
        }
        __syncthreads();

        // ---- tks = clip(round(ws/tsrc * 64 * mult), 1, min(ws-1, Z-1)) ----
        float x = ws / tsrc;     // IEEE f32, identical to jnp
        x *= 64.0f;              // exact (x * 2^6)
        x *= mult;               // single rounding, identical to jnp
        float t = rintf(x);      // half-to-even == jnp.round
        t = fmaxf(1.0f, fminf(t, fminf(ws - 1.0f, (float)(Z - 1))));
        const int tks = (int)t;

        // ---- rank: reproduces lax.top_k order (tie -> lower index) ----
        int rank = 1 << 30;
        if (tid < Z) {
            rank = 0;
            for (int j = 0; j < Z; ++j) {
                const float sj = sc_s[j];
                rank += (int)((sj > myscore) | ((sj == myscore) & (j < tid)));
            }
        }

        const float ws_new = fminf(tsrc, ws * 2.0f);
        const float scale  = ws_new / ws;   // 2.0 exact, or tsrc/2048, or 1.0

        // ---- build bitmap of next-scale pixel values ----
        bm[tid] = 0u;
        __syncthreads();

        if (tid == 0) atomicOr(&bm[0], 1u);  // padded slots contribute value 0
        if (tid < Z && rank < tks_max) {
            const int p  = pix_s[tid];
            const int s0 = (int)rintf((float)p * scale);        // exact product
            atomicOr(&bm[s0 >> 5], 1u << (s0 & 31));
            if (rank < tks) {                                   // positional mask
                const int s1 = (int)rintf((float)(p + 1) * scale);
                if (s1 - s0 >= 2) {
                    const int c = s0 + 1;
                    atomicOr(&bm[c >> 5], 1u << (c & 31));
                }
            }
        }
        __syncthreads();

        // ---- enumerate ascending set bits == sort+dedup, take first max_z ----
        const unsigned int myw = bm[tid];
        int pref = 0;
        for (int j = 0; j < tid; ++j) pref += __popc(bm[j]);
        __syncthreads();
        pix_s[tid] = 0;
        msk_s[tid] = 0;
        __syncthreads();
        unsigned int wv = myw;
        while (wv) {
            if (pref >= max_z) break;
            const int b = __ffs(wv) - 1;
            wv &= wv - 1u;
            pix_s[pref] = (tid << 5) + b;
            msk_s[pref] = 1;
            ++pref;
        }
        __syncthreads();

        ws = ws_new;
        Z  = max_z;
    }

    // ---- final attention over the 64 selected pixels ----
    if (tid < 64) {
        double sfin = -1e30;
        if (msk_s[tid]) {
            const float4* k4 = (const float4*)(kb + (size_t)pix_s[tid] * HID_N);
            const float4* q4 = (const float4*)q_s;
            double acc = 0.0;
            #pragma unroll
            for (int h4 = 0; h4 < HID_N / 4; ++h4) {
                const float4 kv = k4[h4];
                const float4 qv = q4[h4];
                acc = fma((double)qv.x, (double)kv.x, acc);
                acc = fma((double)qv.y, (double)kv.y, acc);
                acc = fma((double)qv.z, (double)kv.z, acc);
                acc = fma((double)qv.w, (double)kv.w, acc);
            }
            sfin = acc;
        }
        double m = sfin;
        #pragma unroll
        for (int off = 32; off > 0; off >>= 1)
            m = fmax(m, __shfl_xor(m, off));
        const double e = exp(sfin - m);      // masked -> exp(-1e30-m) -> 0
        double ssum = e;
        #pragma unroll
        for (int off = 32; off > 0; off >>= 1)
            ssum += __shfl_xor(ssum, off);
        p_s[tid] = e / ssum;
    }
    __syncthreads();

    if (tid < 64) {
        double acc = 0.0;
        for (int j = 0; j < 64; ++j)
            acc = fma(p_s[j], (double)vb[(size_t)pix_s[j] * HID_N + tid], acc);
        out[(size_t)row * HID_N + tid] = (float)acc;
    }
}

extern "C" void kernel_launch(void* const* d_in, const int* in_sizes, int n_in,
                              void* d_out, int out_size, void* d_ws, size_t ws_size,
                              hipStream_t stream) {
    const float* q = (const float*)d_in[0];
    const float* k = (const float*)d_in[1];
    const float* v = (const float*)d_in[2];
    float* out = (float*)d_out;
    const int rows = in_sizes[0] / HID_N;   // N * T_DST = 4096
    tree_attn_kernel<<<rows, 128, 0, stream>>>(q, k, v, out);
}

// Round 4
// 179.987 us; speedup vs baseline: 1.1738x; 1.1738x over previous
//
#include <hip/hip_runtime.h>
#include <math.h>

// TreeAttention: hierarchical top-k mask refinement + sparse attention.
// N=8, T_DST=512, T_SRC=4096, HID=64, K=64, W0=64, SCALE_UP=2, OVERSAMPLE=1.5
//
// One block (128 threads, 2 waves) per (n, a) row; 4096 rows total.
// sort+dedup+truncate == 4096-bit LDS bitmap, ascending enumeration.
// Rank via 39-bit order-preserving key (1 u64 cmp per element),
// prefix-popcount via __shfl_up wave scan. Targets the VALU bound.
// Defensive: bitmap word index clamped (provably in-bounds, but a fault
// here is the only SIGABRT-shaped hazard — 2 VALU of insurance).

#define TSRC_N 4096
#define HID_N  64
#define NEGV   -32000.0f

__global__ __launch_bounds__(128)
void tree_attn_kernel(const float* __restrict__ q,
                      const float* __restrict__ k,
                      const float* __restrict__ v,
                      float* __restrict__ out)
{
    const int row  = blockIdx.x;            // 0..4095
    const int n    = row >> 9;
    const float tsrc = (float)(3585 + (row & 511));
    const int tid  = threadIdx.x;
    const int lane = tid & 63;
    const int wid  = tid >> 6;

    __shared__ __align__(16) float q_s[HID_N];
    __shared__ int                 pix_s[128];
    __shared__ unsigned char       msk_s[128];
    __shared__ unsigned long long  key_s[128];
    __shared__ unsigned int        bm[128];    // 4096-bit presence bitmap
    __shared__ int                 wtot_s[2];
    __shared__ double              p_s[64];

    const float* kb = k + (size_t)n * TSRC_N * HID_N;
    const float* vb = v + (size_t)n * TSRC_N * HID_N;

    if (tid < HID_N) q_s[tid] = q[(size_t)row * HID_N + tid];
    // iteration 0 state: pixels = arange(96), pmask = arange(96) < 64
    pix_s[tid] = tid;
    msk_s[tid] = (tid < 64) ? 1 : 0;
    __syncthreads();

    float ws = 64.0f;
    int Z = 96;

    for (int it = 0; it < 7; ++it) {
        const bool  last    = (it == 6);
        const float mult    = last ? 1.0f : 1.5f;
        const int   tks_max = (it == 0) ? 63 : (last ? 64 : 96);
        const int   max_z   = last ? 64 : 128;

        // ---- scores -> order keys.  key = flip(score)<<7 | (127-idx) so that
        // key_j > key_i  <=>  s_j > s_i  ||  (s_j == s_i && j < i)   (lax.top_k order)
        unsigned long long mykey = 0;
        if (tid < Z) {
            float myscore = NEGV;
            if (msk_s[tid]) {
                const float r = tsrc / ws;                  // exact f32 (pow2 or ==1)
                int tx = (int)rintf((float)pix_s[tid] * r); // exact product, half-even
                tx = tx < (TSRC_N - 1) ? tx : (TSRC_N - 1);
                const float4* k4 = (const float4*)(kb + (size_t)tx * HID_N);
                const float4* q4 = (const float4*)q_s;
                double acc = 0.0;
                #pragma unroll
                for (int h4 = 0; h4 < HID_N / 4; ++h4) {
                    const float4 kv = k4[h4];
                    const float4 qv = q4[h4];
                    acc = fma((double)qv.x, (double)kv.x, acc);
                    acc = fma((double)qv.y, (double)kv.y, acc);
                    acc = fma((double)qv.z, (double)kv.z, acc);
                    acc = fma((double)qv.w, (double)kv.w, acc);
                }
                myscore = (float)acc;
            }
            const unsigned int u  = __float_as_uint(myscore);
            const unsigned int ok = u ^ ((unsigned)((int)u >> 31) | 0x80000000u);
            mykey = ((unsigned long long)ok << 7) | (unsigned)(127 - tid);
        }
        key_s[tid] = mykey;
        bm[tid] = 0u;                      // clear bitmap under the same barrier
        __syncthreads();

        // ---- rank = #{ j : key_j > mykey }  (pad keys are 0, never counted) ----
        int rank = 0;
        {
            #pragma unroll 8
            for (int j = 0; j < 128; ++j)
                rank += (int)(key_s[j] > mykey);
        }

        // ---- tks = clip(round(ws/tsrc * 64 * mult), 1, min(ws-1, Z-1)) ----
        float x = ws / tsrc;
        x *= 64.0f;
        x *= mult;
        float t = rintf(x);
        t = fmaxf(1.0f, fminf(t, fminf(ws - 1.0f, (float)(Z - 1))));
        const int tks = (int)t;

        const float ws_new = fminf(tsrc, ws * 2.0f);
        const float scale  = ws_new / ws;   // 2.0 exact, or tsrc/2048 (exact), or 1.0

        // ---- scatter next-scale pixel values into the bitmap ----
        if (tid == 0) atomicOr(&bm[0], 1u);  // padded top-k slots contribute value 0
        if (tid < Z && rank < tks_max) {
            const int p  = pix_s[tid];
            int s0 = (int)rintf((float)p * scale);        // exact product
            s0 = s0 < (TSRC_N - 1) ? s0 : (TSRC_N - 1);   // defensive clamp
            atomicOr(&bm[s0 >> 5], 1u << (s0 & 31));
            if (rank < tks) {                             // positional rep mask
                const int s1 = (int)rintf((float)(p + 1) * scale);
                if (s1 - s0 >= 2) {
                    const int c = s0 + 1;
                    atomicOr(&bm[c >> 5], 1u << (c & 31));
                }
            }
        }
        __syncthreads();

        // ---- exclusive prefix of popcounts via wave scan (2 waves) ----
        const unsigned int myw = bm[tid];
        const int c = __popc(myw);
        int scan = c;
        #pragma unroll
        for (int off = 1; off < 64; off <<= 1) {
            const int o = __shfl_up(scan, off);
            if (lane >= off) scan += o;
        }
        if (lane == 63) wtot_s[wid] = scan;
        pix_s[tid] = 0;
        msk_s[tid] = 0;
        __syncthreads();
        int pref = scan - c + (wid ? wtot_s[0] : 0);

        // ---- enumerate ascending set bits == sort+dedup, take first max_z ----
        unsigned int wv = myw;
        while (wv) {
            if (pref >= max_z) break;
            const int b = __ffs(wv) - 1;
            wv &= wv - 1u;
            pix_s[pref] = (tid << 5) + b;
            msk_s[pref] = 1;
            ++pref;
        }
        __syncthreads();

        ws = ws_new;
        Z  = max_z;
    }

    // ---- final attention over the 64 selected pixels ----
    if (tid < 64) {
        double sfin = -1e30;
        if (msk_s[tid]) {
            const float4* k4 = (const float4*)(kb + (size_t)pix_s[tid] * HID_N);
            const float4* q4 = (const float4*)q_s;
            double acc = 0.0;
            #pragma unroll
            for (int h4 = 0; h4 < HID_N / 4; ++h4) {
                const float4 kv = k4[h4];
                const float4 qv = q4[h4];
                acc = fma((double)qv.x, (double)kv.x, acc);
                acc = fma((double)qv.y, (double)kv.y, acc);
                acc = fma((double)qv.z, (double)kv.z, acc);
                acc = fma((double)qv.w, (double)kv.w, acc);
            }
            sfin = acc;
        }
        double m = sfin;
        #pragma unroll
        for (int off = 32; off > 0; off >>= 1)
            m = fmax(m, __shfl_xor(m, off));
        const double e = exp(sfin - m);
        double ssum = e;
        #pragma unroll
        for (int off = 32; off > 0; off >>= 1)
            ssum += __shfl_xor(ssum, off);
        p_s[tid] = e / ssum;
    }
    __syncthreads();

    if (tid < 64) {
        double acc = 0.0;
        for (int j = 0; j < 64; ++j)
            acc = fma(p_s[j], (double)vb[(size_t)pix_s[j] * HID_N + tid], acc);
        out[(size_t)row * HID_N + tid] = (float)acc;
    }
}

extern "C" void kernel_launch(void* const* d_in, const int* in_sizes, int n_in,
                              void* d_out, int out_size, void* d_ws, size_t ws_size,
                              hipStream_t stream) {
    const float* q = (const float*)d_in[0];
    const float* k = (const float*)d_in[1];
    const float* v = (const float*)d_in[2];
    float* out = (float*)d_out;
    const int rows = in_sizes[0] / HID_N;   // N * T_DST = 4096
    tree_attn_kernel<<<rows, 128, 0, stream>>>(q, k, v, out);
}

// Round 6
// 166.639 us; speedup vs baseline: 1.2679x; 1.0801x over previous
//
#include <hip/hip_runtime.h>
#include <math.h>

// TreeAttention: hierarchical top-k mask refinement + sparse attention.
// N=8, T_DST=512, T_SRC=4096, HID=64, K=64, W0=64, SCALE_UP=2, OVERSAMPLE=1.5
//
// Round 5 design (resubmitted round 6 — round 5 bench lost to broker timeout):
// ONE ROW PER 64-LANE WAVE (grid=4096, block=64).
//  - u32 flipped-float keys (index tie-break dropped: ties occur only among
//    masked slots, which all carry pix=0 -> scatter bit 0, set anyway).
//  - rank: 2 elements/lane share uint4 LDS key reads (32 b128 reads/row).
//  - q in SGPRs via uniform s_load (row = blockIdx.x); f32 scoring, f32
//    softmax (__expf) and f32 PV — matches reference f32 einsum dtype.
//  - bitmap sort+dedup as before; prefix via single-wave __shfl_up scan.

#define TSRC_N 4096
#define HID_N  64
#define NEGV   -32000.0f

__global__ __launch_bounds__(64)
void tree_attn_kernel(const float* __restrict__ q,
                      const float* __restrict__ k,
                      const float* __restrict__ v,
                      float* __restrict__ out)
{
    const int row  = blockIdx.x;            // 0..4095, wave-uniform
    const int n    = row >> 9;
    const float tsrc = (float)(3585 + (row & 511));
    const int lane = threadIdx.x;           // 0..63

    __shared__ __align__(16) unsigned int key_s[128];
    __shared__ __align__(16) unsigned int bm[128];   // 4096-bit presence bitmap
    __shared__ int                        pix_s[128];
    __shared__ unsigned char              msk_s[128];
    __shared__ __align__(8) unsigned int  pp_s[128]; // packed {p_bits, pix} pairs

    const float* qrow = q + (size_t)row * HID_N;     // uniform -> s_load
    const float* kb   = k + (size_t)n * TSRC_N * HID_N;
    const float* vb   = v + (size_t)n * TSRC_N * HID_N;

    // f32 dot of q (SGPR-resident) with gathered k row; 4 partials for ILP.
    auto dot_f32 = [&](int tx) -> float {
        const float4* k4 = (const float4*)(kb + (size_t)tx * HID_N);
        float a0 = 0.f, a1 = 0.f, a2 = 0.f, a3 = 0.f;
        #pragma unroll
        for (int h4 = 0; h4 < HID_N / 4; ++h4) {
            const float4 kv = k4[h4];
            a0 = fmaf(kv.x, qrow[h4 * 4 + 0], a0);
            a1 = fmaf(kv.y, qrow[h4 * 4 + 1], a1);
            a2 = fmaf(kv.z, qrow[h4 * 4 + 2], a2);
            a3 = fmaf(kv.w, qrow[h4 * 4 + 3], a3);
        }
        return (a0 + a1) + (a2 + a3);
    };
    // order-preserving f32 -> u32 flip (key 0 reserved for absent slots)
    auto flip32 = [](float s) -> unsigned int {
        const unsigned int u = __float_as_uint(s);
        return u ^ ((unsigned)((int)u >> 31) | 0x80000000u);
    };

    // iteration 0 state: pixels = arange(96), pmask = arange(96) < 64
    pix_s[lane]      = lane;
    pix_s[lane + 64] = lane + 64;
    msk_s[lane]      = 1;
    msk_s[lane + 64] = 0;
    __syncthreads();

    float ws = 64.0f;
    int Z = 96;

    for (int it = 0; it < 7; ++it) {
        const bool  last    = (it == 6);
        const float mult    = last ? 1.0f : 1.5f;
        const int   tks_max = (it == 0) ? 63 : (last ? 64 : 96);
        const int   max_z   = last ? 64 : 128;
        const int   e1      = lane + 64;

        // ---- scores -> u32 keys (two elements per lane) ----
        const float r = tsrc / ws;                 // exact f32 (pow2 ratio or 1)
        unsigned int key0 = 0, key1 = 0;
        {
            float s0 = NEGV;
            if (msk_s[lane]) {
                int tx = (int)rintf((float)pix_s[lane] * r);
                tx = tx < (TSRC_N - 1) ? tx : (TSRC_N - 1);
                s0 = dot_f32(tx);
            }
            key0 = flip32(s0);
        }
        if (e1 < Z) {
            float s1 = NEGV;
            if (msk_s[e1]) {
                int tx = (int)rintf((float)pix_s[e1] * r);
                tx = tx < (TSRC_N - 1) ? tx : (TSRC_N - 1);
                s1 = dot_f32(tx);
            }
            key1 = flip32(s1);
        }
        key_s[lane] = key0;
        key_s[e1]   = key1;
        bm[lane]    = 0u;
        bm[e1]      = 0u;
        __syncthreads();

        // ---- ranks: count strictly-greater keys (1 uint4 read serves both) ----
        int r0 = 0, r1 = 0;
        #pragma unroll 8
        for (int j = 0; j < 128; j += 4) {
            const uint4 kk = *(const uint4*)&key_s[j];
            r0 += (int)(kk.x > key0) + (int)(kk.y > key0)
                + (int)(kk.z > key0) + (int)(kk.w > key0);
            r1 += (int)(kk.x > key1) + (int)(kk.y > key1)
                + (int)(kk.z > key1) + (int)(kk.w > key1);
        }

        // ---- tks = clip(round(ws/tsrc * 64 * mult), 1, min(ws-1, Z-1)) ----
        float x = ws / tsrc;
        x *= 64.0f;
        x *= mult;
        float t = rintf(x);
        t = fmaxf(1.0f, fminf(t, fminf(ws - 1.0f, (float)(Z - 1))));
        const int tks = (int)t;

        const float ws_new = fminf(tsrc, ws * 2.0f);
        const float scale  = ws_new / ws;     // 2.0, tsrc/2048, or 1.0 (exact)

        // ---- scatter next-scale values into the bitmap ----
        if (lane == 0) atomicOr(&bm[0], 1u);  // padded top-k slots -> value 0
        if (r0 < tks_max) {
            const int p  = pix_s[lane];
            int s0 = (int)rintf((float)p * scale);
            s0 = s0 < (TSRC_N - 1) ? s0 : (TSRC_N - 1);
            atomicOr(&bm[s0 >> 5], 1u << (s0 & 31));
            if (r0 < tks) {
                const int s1i = (int)rintf((float)(p + 1) * scale);
                if (s1i - s0 >= 2) {
                    const int c = s0 + 1;
                    atomicOr(&bm[c >> 5], 1u << (c & 31));
                }
            }
        }
        if (e1 < Z && r1 < tks_max) {
            const int p  = pix_s[e1];
            int s0 = (int)rintf((float)p * scale);
            s0 = s0 < (TSRC_N - 1) ? s0 : (TSRC_N - 1);
            atomicOr(&bm[s0 >> 5], 1u << (s0 & 31));
            if (r1 < tks) {
                const int s1i = (int)rintf((float)(p + 1) * scale);
                if (s1i - s0 >= 2) {
                    const int c = s0 + 1;
                    atomicOr(&bm[c >> 5], 1u << (c & 31));
                }
            }
        }
        __syncthreads();

        // ---- exclusive prefix of popcounts; lane owns words 2L, 2L+1 ----
        const uint2 w2 = *(const uint2*)&bm[2 * lane];
        const int c = __popc(w2.x) + __popc(w2.y);
        int scan = c;
        #pragma unroll
        for (int off = 1; off < 64; off <<= 1) {
            const int o = __shfl_up(scan, off);
            if (lane >= off) scan += o;
        }
        int pref = scan - c;                  // exclusive prefix
        pix_s[lane] = 0;  pix_s[e1] = 0;
        msk_s[lane] = 0;  msk_s[e1] = 0;
        __syncthreads();

        // ---- enumerate ascending set bits == sort+dedup, first max_z ----
        unsigned int wv = w2.x;
        int base = lane << 6;                 // word 2L covers values 64L..
        while (wv) {
            if (pref >= max_z) break;
            const int b = __ffs(wv) - 1;
            wv &= wv - 1u;
            pix_s[pref] = base + b;
            msk_s[pref] = 1;
            ++pref;
        }
        wv = w2.y;
        base += 32;
        while (wv) {
            if (pref >= max_z) break;
            const int b = __ffs(wv) - 1;
            wv &= wv - 1u;
            pix_s[pref] = base + b;
            msk_s[pref] = 1;
            ++pref;
        }
        __syncthreads();

        ws = ws_new;
        Z  = max_z;
    }

    // ---- final attention over the 64 selected pixels (f32, matches ref) ----
    {
        const int pix = pix_s[lane];
        float sfin = -1e30f;
        if (msk_s[lane]) sfin = dot_f32(pix);
        float m = sfin;
        #pragma unroll
        for (int off = 32; off > 0; off >>= 1)
            m = fmaxf(m, __shfl_xor(m, off));
        const float e = __expf(sfin - m);     // masked -> 0
        float ssum = e;
        #pragma unroll
        for (int off = 32; off > 0; off >>= 1)
            ssum += __shfl_xor(ssum, off);
        const float p = e / ssum;
        pp_s[2 * lane]     = __float_as_uint(p);
        pp_s[2 * lane + 1] = (unsigned int)pix;
    }
    __syncthreads();

    {
        float acc = 0.f;
        #pragma unroll 4
        for (int j = 0; j < 64; ++j) {
            const uint2 pp = *(const uint2*)&pp_s[2 * j];
            acc = fmaf(__uint_as_float(pp.x),
                       vb[(size_t)pp.y * HID_N + lane], acc);
        }
        out[(size_t)row * HID_N + lane] = acc;
    }
}

extern "C" void kernel_launch(void* const* d_in, const int* in_sizes, int n_in,
                              void* d_out, int out_size, void* d_ws, size_t ws_size,
                              hipStream_t stream) {
    const float* q = (const float*)d_in[0];
    const float* k = (const float*)d_in[1];
    const float* v = (const float*)d_in[2];
    float* out = (float*)d_out;
    const int rows = in_sizes[0] / HID_N;   // N * T_DST = 4096
    tree_attn_kernel<<<rows, 64, 0, stream>>>(q, k, v, out);
}

// Round 7
// 163.884 us; speedup vs baseline: 1.2892x; 1.0168x over previous
//
#include <hip/hip_runtime.h>
#include <math.h>

// TreeAttention: hierarchical top-k mask refinement + sparse attention.
// N=8, T_DST=512, T_SRC=4096, HID=64, K=64, W0=64, SCALE_UP=2, OVERSAMPLE=1.5
//
// Round 7: FOUR ROWS PER 256-THREAD BLOCK, one row per 64-lane wave,
// private LDS slice per wave, NO inter-wave barriers (wave_barrier only).
// Attacks round 6's occupancy collapse (33%: 64-thd workgroups hit the
// per-CU workgroup-slot limit). Now 4 waves/wg-slot -> up to 32 waves/CU.
//  - u32 flipped-float keys (index tie-break provably unnecessary).
//  - rank: 2 elements/lane share uint4 LDS key reads (broadcast, no conflict).
//  - q via uniform s_load (row made wave-uniform with readfirstlane).
//  - bitmap sort+dedup; prefix via single-wave __shfl_up scan.

#define TSRC_N 4096
#define HID_N  64
#define NEGV   -32000.0f

__global__ __launch_bounds__(256)
void tree_attn_kernel(const float* __restrict__ q,
                      const float* __restrict__ k,
                      const float* __restrict__ v,
                      float* __restrict__ out)
{
    // wave-uniform wave id (readfirstlane keeps row uniform -> q s_load)
    const int wid  = __builtin_amdgcn_readfirstlane((int)(threadIdx.x >> 6));
    const int lane = threadIdx.x & 63;
    const int row  = (blockIdx.x << 2) + wid;        // 0..4095, wave-uniform
    const int n    = row >> 9;
    const float tsrc = (float)(3585 + (row & 511));

    // per-wave private LDS slices — no cross-wave sharing, no __syncthreads
    __shared__ __align__(16) unsigned int key_s[4][128];
    __shared__ __align__(16) unsigned int bm[4][128];   // 4096-bit bitmaps
    __shared__ int                        pix_s[4][128];
    __shared__ unsigned char              msk_s[4][128];
    __shared__ __align__(8) unsigned int  pp_s[4][128]; // {p_bits, pix} pairs
    unsigned int* const keyw = key_s[wid];
    unsigned int* const bmw  = bm[wid];
    int* const           pixw = pix_s[wid];
    unsigned char* const mskw = msk_s[wid];
    unsigned int* const  ppw  = pp_s[wid];

    const float* qrow = q + (size_t)row * HID_N;     // uniform -> s_load
    const float* kb   = k + (size_t)n * TSRC_N * HID_N;
    const float* vb   = v + (size_t)n * TSRC_N * HID_N;

    // f32 dot of q (SGPR-resident) with gathered k row; 4 partials for ILP.
    auto dot_f32 = [&](int tx) -> float {
        const float4* k4 = (const float4*)(kb + (size_t)tx * HID_N);
        float a0 = 0.f, a1 = 0.f, a2 = 0.f, a3 = 0.f;
        #pragma unroll
        for (int h4 = 0; h4 < HID_N / 4; ++h4) {
            const float4 kv = k4[h4];
            a0 = fmaf(kv.x, qrow[h4 * 4 + 0], a0);
            a1 = fmaf(kv.y, qrow[h4 * 4 + 1], a1);
            a2 = fmaf(kv.z, qrow[h4 * 4 + 2], a2);
            a3 = fmaf(kv.w, qrow[h4 * 4 + 3], a3);
        }
        return (a0 + a1) + (a2 + a3);
    };
    // order-preserving f32 -> u32 flip (key 0 reserved for absent slots)
    auto flip32 = [](float s) -> unsigned int {
        const unsigned int u = __float_as_uint(s);
        return u ^ ((unsigned)((int)u >> 31) | 0x80000000u);
    };

    // iteration 0 state: pixels = arange(96), pmask = arange(96) < 64
    pixw[lane]      = lane;
    pixw[lane + 64] = lane + 64;
    mskw[lane]      = 1;
    mskw[lane + 64] = 0;
    __builtin_amdgcn_wave_barrier();

    float ws = 64.0f;
    int Z = 96;

    for (int it = 0; it < 7; ++it) {
        const bool  last    = (it == 6);
        const float mult    = last ? 1.0f : 1.5f;
        const int   tks_max = (it == 0) ? 63 : (last ? 64 : 96);
        const int   max_z   = last ? 64 : 128;
        const int   e1      = lane + 64;

        // ---- scores -> u32 keys (two elements per lane) ----
        const float r = tsrc / ws;                 // exact f32 (pow2 ratio or 1)
        unsigned int key0 = 0, key1 = 0;
        {
            float s0 = NEGV;
            if (mskw[lane]) {
                int tx = (int)rintf((float)pixw[lane] * r);
                tx = tx < (TSRC_N - 1) ? tx : (TSRC_N - 1);
                s0 = dot_f32(tx);
            }
            key0 = flip32(s0);
        }
        if (e1 < Z) {
            float s1 = NEGV;
            if (mskw[e1]) {
                int tx = (int)rintf((float)pixw[e1] * r);
                tx = tx < (TSRC_N - 1) ? tx : (TSRC_N - 1);
                s1 = dot_f32(tx);
            }
            key1 = flip32(s1);
        }
        keyw[lane] = key0;
        keyw[e1]   = key1;
        bmw[lane]  = 0u;
        bmw[e1]    = 0u;
        __builtin_amdgcn_wave_barrier();

        // ---- ranks: count strictly-greater keys (1 uint4 read serves both) ----
        int r0 = 0, r1 = 0;
        #pragma unroll 8
        for (int j = 0; j < 128; j += 4) {
            const uint4 kk = *(const uint4*)&keyw[j];
            r0 += (int)(kk.x > key0) + (int)(kk.y > key0)
                + (int)(kk.z > key0) + (int)(kk.w > key0);
            r1 += (int)(kk.x > key1) + (int)(kk.y > key1)
                + (int)(kk.z > key1) + (int)(kk.w > key1);
        }

        // ---- tks = clip(round(ws/tsrc * 64 * mult), 1, min(ws-1, Z-1)) ----
        float x = ws / tsrc;
        x *= 64.0f;
        x *= mult;
        float t = rintf(x);
        t = fmaxf(1.0f, fminf(t, fminf(ws - 1.0f, (float)(Z - 1))));
        const int tks = (int)t;

        const float ws_new = fminf(tsrc, ws * 2.0f);
        const float scale  = ws_new / ws;     // 2.0, tsrc/2048, or 1.0 (exact)

        // ---- scatter next-scale values into the bitmap ----
        if (lane == 0) atomicOr(&bmw[0], 1u); // padded top-k slots -> value 0
        if (r0 < tks_max) {
            const int p  = pixw[lane];
            int s0 = (int)rintf((float)p * scale);
            s0 = s0 < (TSRC_N - 1) ? s0 : (TSRC_N - 1);
            atomicOr(&bmw[s0 >> 5], 1u << (s0 & 31));
            if (r0 < tks) {
                const int s1i = (int)rintf((float)(p + 1) * scale);
                if (s1i - s0 >= 2) {
                    const int c = s0 + 1;
                    atomicOr(&bmw[c >> 5], 1u << (c & 31));
                }
            }
        }
        if (e1 < Z && r1 < tks_max) {
            const int p  = pixw[e1];
            int s0 = (int)rintf((float)p * scale);
            s0 = s0 < (TSRC_N - 1) ? s0 : (TSRC_N - 1);
            atomicOr(&bmw[s0 >> 5], 1u << (s0 & 31));
            if (r1 < tks) {
                const int s1i = (int)rintf((float)(p + 1) * scale);
                if (s1i - s0 >= 2) {
                    const int c = s0 + 1;
                    atomicOr(&bmw[c >> 5], 1u << (c & 31));
                }
            }
        }
        __builtin_amdgcn_wave_barrier();

        // ---- exclusive prefix of popcounts; lane owns words 2L, 2L+1 ----
        const uint2 w2 = *(const uint2*)&bmw[2 * lane];
        const int c = __popc(w2.x) + __popc(w2.y);
        int scan = c;
        #pragma unroll
        for (int off = 1; off < 64; off <<= 1) {
            const int o = __shfl_up(scan, off);
            if (lane >= off) scan += o;
        }
        int pref = scan - c;                  // exclusive prefix
        pixw[lane] = 0;  pixw[e1] = 0;
        mskw[lane] = 0;  mskw[e1] = 0;
        __builtin_amdgcn_wave_barrier();

        // ---- enumerate ascending set bits == sort+dedup, first max_z ----
        unsigned int wv = w2.x;
        int base = lane << 6;                 // word 2L covers values 64L..
        while (wv) {
            if (pref >= max_z) break;
            const int b = __ffs(wv) - 1;
            wv &= wv - 1u;
            pixw[pref] = base + b;
            mskw[pref] = 1;
            ++pref;
        }
        wv = w2.y;
        base += 32;
        while (wv) {
            if (pref >= max_z) break;
            const int b = __ffs(wv) - 1;
            wv &= wv - 1u;
            pixw[pref] = base + b;
            mskw[pref] = 1;
            ++pref;
        }
        __builtin_amdgcn_wave_barrier();

        ws = ws_new;
        Z  = max_z;
    }

    // ---- final attention over the 64 selected pixels (f32, matches ref) ----
    {
        const int pix = pixw[lane];
        float sfin = -1e30f;
        if (mskw[lane]) sfin = dot_f32(pix);
        float m = sfin;
        #pragma unroll
        for (int off = 32; off > 0; off >>= 1)
            m = fmaxf(m, __shfl_xor(m, off));
        const float e = __expf(sfin - m);     // masked -> 0
        float ssum = e;
        #pragma unroll
        for (int off = 32; off > 0; off >>= 1)
            ssum += __shfl_xor(ssum, off);
        const float p = e / ssum;
        ppw[2 * lane]     = __float_as_uint(p);
        ppw[2 * lane + 1] = (unsigned int)pix;
    }
    __builtin_amdgcn_wave_barrier();

    {
        float acc = 0.f;
        #pragma unroll 4
        for (int j = 0; j < 64; ++j) {
            const uint2 pp = *(const uint2*)&ppw[2 * j];
            acc = fmaf(__uint_as_float(pp.x),
                       vb[(size_t)pp.y * HID_N + lane], acc);
        }
        out[(size_t)row * HID_N + lane] = acc;
    }
}

extern "C" void kernel_launch(void* const* d_in, const int* in_sizes, int n_in,
                              void* d_out, int out_size, void* d_ws, size_t ws_size,
                              hipStream_t stream) {
    const float* q = (const float*)d_in[0];
    const float* k = (const float*)d_in[1];
    const float* v = (const float*)d_in[2];
    float* out = (float*)d_out;
    const int rows = in_sizes[0] / HID_N;   // N * T_DST = 4096
    tree_attn_kernel<<<(rows + 3) / 4, 256, 0, stream>>>(q, k, v, out);
}